// Round 15
// baseline (755.995 us; speedup 1.0000x reference)
//
#include <hip/hip_runtime.h>
#include <stdint.h>

typedef _Float16 half8 __attribute__((ext_vector_type(8)));
typedef float f32x4 __attribute__((ext_vector_type(4)));

#define DDIM 256
#define KCODES 4096
#define BM 128
#define BN 128
#define DELTA 0.10f
#define FLT_BIG 3.4e38f

#define GLOAD_LDS(gsrc, ldst)                                                        \
    __builtin_amdgcn_global_load_lds(                                                \
        (const __attribute__((address_space(1))) void*)(const void*)(gsrc),          \
        (__attribute__((address_space(3))) void*)(void*)(ldst), 16, 0, 0)

// ---------- fp32 -> fp16 (hi only), layout [row][slot(32)] half8 ----------
// slot s holds dims s*8 .. s*8+7
__global__ void cvt_h_kernel(const float* __restrict__ src, half8* __restrict__ dst) {
    int gid = blockIdx.x * 256 + threadIdx.x;   // rows*32 threads
    int s = gid & 31;
    long row = gid >> 5;
    const float* p = src + row * DDIM + s * 8;
    const float4 f0 = ((const float4*)p)[0];
    const float4 f1 = ((const float4*)p)[1];
    half8 h;
    h[0] = (_Float16)f0.x; h[1] = (_Float16)f0.y;
    h[2] = (_Float16)f0.z; h[3] = (_Float16)f0.w;
    h[4] = (_Float16)f1.x; h[5] = (_Float16)f1.y;
    h[6] = (_Float16)f1.z; h[7] = (_Float16)f1.w;
    dst[gid] = h;
}

__global__ void enorm_kernel(const float* __restrict__ cb, float* __restrict__ en, int K) {
    int gid = blockIdx.x * blockDim.x + threadIdx.x;
    int code = gid >> 6;
    int lane = threadIdx.x & 63;
    if (code >= K) return;
    const float4 v = *reinterpret_cast<const float4*>(&cb[(size_t)code * DDIM + lane * 4]);
    float s = v.x * v.x + v.y * v.y + v.z * v.z + v.w * v.w;
    #pragma unroll
    for (int off = 32; off > 0; off >>= 1) s += __shfl_xor(s, off, 64);
    if (lane == 0) en[code] = s;
}

// ---------------- main: hi-only 1-term MFMA, K=64 steps, stage-after-barrier ----------------
__global__ __launch_bounds__(256, 2)
void vq_mfma_kernel(const half8* x16, const half8* __restrict__ cb16,
                    const float* __restrict__ en, int* __restrict__ bidx,
                    int* __restrict__ list, int* __restrict__ counter) {
    __shared__ __align__(16) half8 Abuf[2][BM * 8];   // 2 x 16 KB (128 rows x 8 slots)
    __shared__ __align__(16) half8 Bbuf[2][BN * 8];   // 2 x 16 KB
    __shared__ float red_d[2][BM];
    __shared__ float red_d2[2][BM];
    __shared__ int   red_i[2][BM];

    const int tid = threadIdx.x;
    const int lane = tid & 63;
    const int w = tid >> 6;                  // 4 waves
    const int wr = w >> 1, wc = w & 1;       // 2 x 2, wave-tile 64 rows x 64 codes
    const int l15 = lane & 15, l4 = lane >> 4;
    const int brow = blockIdx.x * BM;

    // ---- persistent stage pointers: 4 A-regions + 4 B-regions per wave ----
    const int lrow = lane >> 3;          // row within 8-row region
    const int swz = (lane & 7) ^ lrow;   // pre-swizzled slot within the 8-slot window
    const half8* pA0 = x16 + (size_t)(brow + (w     ) * 8 + lrow) * 32 + swz;
    const half8* pA1 = x16 + (size_t)(brow + (w +  4) * 8 + lrow) * 32 + swz;
    const half8* pA2 = x16 + (size_t)(brow + (w +  8) * 8 + lrow) * 32 + swz;
    const half8* pA3 = x16 + (size_t)(brow + (w + 12) * 8 + lrow) * 32 + swz;
    const half8* pB0 = cb16 + (size_t)((w     ) * 8 + lrow) * 32 + swz;
    const half8* pB1 = cb16 + (size_t)((w +  4) * 8 + lrow) * 32 + swz;
    const half8* pB2 = cb16 + (size_t)((w +  8) * 8 + lrow) * 32 + swz;
    const half8* pB3 = cb16 + (size_t)((w + 12) * 8 + lrow) * 32 + swz;

#define STAGE(b_) do {                                      \
        GLOAD_LDS(pA0, &Abuf[b_][(w     ) * 64]);           \
        GLOAD_LDS(pA1, &Abuf[b_][(w +  4) * 64]);           \
        GLOAD_LDS(pA2, &Abuf[b_][(w +  8) * 64]);           \
        GLOAD_LDS(pA3, &Abuf[b_][(w + 12) * 64]);           \
        GLOAD_LDS(pB0, &Bbuf[b_][(w     ) * 64]);           \
        GLOAD_LDS(pB1, &Bbuf[b_][(w +  4) * 64]);           \
        GLOAD_LDS(pB2, &Bbuf[b_][(w +  8) * 64]);           \
        GLOAD_LDS(pB3, &Bbuf[b_][(w + 12) * 64]);           \
    } while (0)

#define ADVA(dA_, dB_) do {                                 \
        pA0 += dA_; pA1 += dA_; pA2 += dA_; pA3 += dA_;     \
        pB0 += dB_; pB1 += dB_; pB2 += dB_; pB3 += dB_;     \
    } while (0)

    // ---- LDS frag read bases (halfword units); kk=1 slot = slot0 ^ 4 ----
    const int sw7 = l15 & 7;
    const int s0 = l4 ^ sw7;
    const _Float16* A0 = (const _Float16*)Abuf;
    const _Float16* B0 = A0 + 16384;
    const _Float16* aH0 = A0 + (wr * 64 + l15) * 64 + s0 * 8;
    const _Float16* aH1 = A0 + (wr * 64 + l15) * 64 + (s0 ^ 4) * 8;
    const _Float16* bH0 = B0 + (wc * 64 + l15) * 64 + s0 * 8;
    const _Float16* bH1 = B0 + (wc * 64 + l15) * 64 + (s0 ^ 4) * 8;

    // prologue: stage (tile0, window0) into buf0
    STAGE(0); ADVA(8, 8);

    float bestv[4], best2v[4];
    int bidv[4];
    #pragma unroll
    for (int i = 0; i < 4; ++i) { bestv[i] = FLT_BIG; best2v[i] = FLT_BIG; bidv[i] = 0; }

    const int code_sub = wc * 64 + l4 * 4;
    f32x4 acc[4][4];

    for (int it = 0; it < 32; ++it) {
        #pragma unroll
        for (int m = 0; m < 4; ++m)
            #pragma unroll
            for (int n = 0; n < 4; ++n) acc[m][n] = (f32x4){0.f, 0.f, 0.f, 0.f};

        #pragma unroll
        for (int k = 0; k < 4; ++k) {        // 4 steps x K=64
            // drains the stage issued one full step earlier, then publishes
            __syncthreads();
            if (k != 3) {
                STAGE((k + 1) & 1);                  // window k+1, same tile
                if (k == 2) ADVA(-24, 4072);         // staged window3 -> next tile w0
                else        ADVA(8, 8);
            } else if (it != 31) {
                STAGE(0);                            // next tile, window 0
                ADVA(8, 8);
            }
            __builtin_amdgcn_sched_barrier(0);       // pin stage issue before reads/MFMA

            const int o = (k & 1) ? 8192 : 0;
            half8 a0[4], a1[4], b0[4], b1[4];
            #pragma unroll
            for (int i = 0; i < 4; ++i) {
                a0[i] = *(const half8*)(aH0 + o + i * 1024);
                a1[i] = *(const half8*)(aH1 + o + i * 1024);
                b0[i] = *(const half8*)(bH0 + o + i * 1024);
                b1[i] = *(const half8*)(bH1 + o + i * 1024);
            }
            __builtin_amdgcn_s_setprio(1);
            #pragma unroll
            for (int m = 0; m < 4; ++m)
                #pragma unroll
                for (int n = 0; n < 4; ++n) {
                    acc[m][n] = __builtin_amdgcn_mfma_f32_16x16x32_f16(b0[m], a0[n], acc[m][n], 0, 0, 0);
                    acc[m][n] = __builtin_amdgcn_mfma_f32_16x16x32_f16(b1[m], a1[n], acc[m][n], 0, 0, 0);
                }
            __builtin_amdgcn_s_setprio(0);
        }

        // ---- tile epilogue: dist = ||e||^2 - 2*dot (en from global/L2) ----
        const int c0 = it * BN;
        #pragma unroll
        for (int m = 0; m < 4; ++m) {
            const float4 e4 = *(const float4*)(en + c0 + wc * 64 + m * 16 + l4 * 4);
            #pragma unroll
            for (int r = 0; r < 4; ++r) {
                int code = c0 + code_sub + m * 16 + r;
                float e = (r == 0) ? e4.x : (r == 1) ? e4.y : (r == 2) ? e4.z : e4.w;
                #pragma unroll
                for (int n = 0; n < 4; ++n) {
                    float dist = fmaf(-2.f, acc[m][n][r], e);
                    if (dist < bestv[n]) { best2v[n] = bestv[n]; bestv[n] = dist; bidv[n] = code; }
                    else if (dist < best2v[n]) best2v[n] = dist;
                }
            }
        }
    }
#undef STAGE
#undef ADVA

    // ---- cross-lane merge: candidates for row (wr*64+n*16+l15) spread over l4 ----
    #pragma unroll
    for (int n = 0; n < 4; ++n) {
        float d = bestv[n], d2 = best2v[n];
        int ix = bidv[n];
        #pragma unroll
        for (int off = 16; off < 64; off <<= 1) {
            float od = __shfl_xor(d, off, 64);
            float od2 = __shfl_xor(d2, off, 64);
            int oi = __shfl_xor(ix, off, 64);
            if (od < d || (od == d && oi < ix)) { d2 = fminf(d, od2); d = od; ix = oi; }
            else d2 = fminf(d2, od);
        }
        if (l4 == 0) {
            int row = wr * 64 + n * 16 + l15;
            red_d[wc][row] = d;
            red_d2[wc][row] = d2;
            red_i[wc][row] = ix;
        }
    }
    __syncthreads();

    // ---- cross-wave merge + bidx write + flag append ----
    if (tid < BM) {
        float d = red_d[0][tid], d2 = red_d2[0][tid];
        int ix = red_i[0][tid];
        float od = red_d[1][tid], od2 = red_d2[1][tid];
        int oi = red_i[1][tid];
        if (od < d || (od == d && oi < ix)) { d2 = fminf(d, od2); d = od; ix = oi; }
        else d2 = fminf(d2, od);
        bidx[brow + tid] = ix;
        if (d2 - d < DELTA) {
            int pos = atomicAdd(counter, 1);
            list[pos] = brow + tid;
        }
    }
}

// ---------------- exact fp32 rescan: repairs bidx for flagged rows ----------------
__global__ __launch_bounds__(256)
void rescan_kernel(const float* __restrict__ x, const float* __restrict__ cb,
                   const float* __restrict__ en, const int* __restrict__ list,
                   const int* __restrict__ counter, int* __restrict__ bidx) {
    __shared__ __align__(16) float4 xrow4[64];
    __shared__ float wd[4];
    __shared__ int wi[4];
    const int tid = threadIdx.x;
    const int w = tid >> 6;
    const int lane = tid & 63;
    const int cnt = *counter;

    for (int it = blockIdx.x; it < cnt; it += gridDim.x) {
        const int row = list[it];
        __syncthreads();
        if (tid < 64) xrow4[tid] = ((const float4*)&x[(size_t)row * DDIM])[tid];
        __syncthreads();
        const float4 xv = xrow4[lane];
        float bd = FLT_BIG;
        int bi = 0;
        for (int i = 0; i < KCODES / 4; ++i) {
            int code = i * 4 + w;
            const float4 c4 = ((const float4*)&cb[(size_t)code * DDIM])[lane];
            float s = xv.x * c4.x + xv.y * c4.y + xv.z * c4.z + xv.w * c4.w;
            #pragma unroll
            for (int off = 1; off < 64; off <<= 1) s += __shfl_xor(s, off, 64);
            float dist = fmaf(-2.f, s, en[code]);
            if (dist < bd) { bd = dist; bi = code; }
        }
        if (lane == 0) { wd[w] = bd; wi[w] = bi; }
        __syncthreads();
        if (tid == 0) {
            float d = wd[0]; int ix = wi[0];
            #pragma unroll
            for (int q = 1; q < 4; ++q) {
                if (wd[q] < d || (wd[q] == d && wi[q] < ix)) { d = wd[q]; ix = wi[q]; }
            }
            bidx[row] = ix;
        }
    }
}

// ---------------- gather + loss + indices (all rows, final bidx) ----------------
__global__ __launch_bounds__(256)
void gather_kernel(const float* __restrict__ x, const float* __restrict__ cb,
                   const int* __restrict__ bidx, float* __restrict__ out,
                   float* __restrict__ loss_accum, int N) {
    __shared__ float wsum[4];
    __shared__ int bloc[64];
    const int tid = threadIdx.x;
    const int brow = blockIdx.x * 64;
    const size_t ND = (size_t)N * DDIM;
    if (tid < 64) {
        int ix = bidx[brow + tid];
        bloc[tid] = ix;
        out[ND + 1 + brow + tid] = (float)ix;
    }
    __syncthreads();
    float lsum = 0.f;
    #pragma unroll
    for (int pp = 0; pp < 16; ++pp) {
        int i = tid + pp * 256;       // 0..4095 float4-units
        int row = i >> 6;
        int c4 = (i & 63) << 2;
        int code = bloc[row];
        const float4 q = *reinterpret_cast<const float4*>(&cb[(size_t)code * DDIM + c4]);
        const float4 xv = *reinterpret_cast<const float4*>(&x[(size_t)(brow + row) * DDIM + c4]);
        float d0 = xv.x - q.x, d1 = xv.y - q.y, d2 = xv.z - q.z, d3 = xv.w - q.w;
        lsum += d0 * d0 + d1 * d1 + d2 * d2 + d3 * d3;
        *reinterpret_cast<float4*>(&out[(size_t)(brow + row) * DDIM + c4]) = q;
    }
    #pragma unroll
    for (int off = 32; off > 0; off >>= 1) lsum += __shfl_xor(lsum, off, 64);
    if ((tid & 63) == 0) wsum[tid >> 6] = lsum;
    __syncthreads();
    if (tid == 0) {
        float tot = wsum[0] + wsum[1] + wsum[2] + wsum[3];
        atomicAdd(loss_accum, tot * (0.25f / (float)ND));
    }
}

__global__ void loss_fin_kernel(const float* __restrict__ loss_accum,
                                float* __restrict__ out, size_t off) {
    if (blockIdx.x == 0 && threadIdx.x == 0) out[off] = *loss_accum;
}

extern "C" void kernel_launch(void* const* d_in, const int* in_sizes, int n_in,
                              void* d_out, int out_size, void* d_ws, size_t ws_size,
                              hipStream_t stream) {
    const float* x = (const float*)d_in[0];
    const float* cb = (const float*)d_in[1];
    const int N = in_sizes[0] / DDIM;    // 65536
    const int K = in_sizes[1] / DDIM;    // 4096
    float* out = (float*)d_out;

    // x16 (32 MB, hi-only) lives in out[0 .. N*D) — overwritten by gather afterwards
    half8* x16 = (half8*)d_out;

    half8* cb16 = (half8*)d_ws;          // 2 MB hi-only codebook
    char* p = (char*)d_ws + (2 << 20);
    float* en = (float*)p;                  p += (size_t)K * 4;
    int* bidx = (int*)p;                    p += (size_t)N * 4;
    int* list = (int*)p;                    p += (size_t)N * 4;
    int* counter = (int*)p;                 p += 64;
    float* loss_accum = (float*)p;

    hipMemsetAsync(counter, 0, sizeof(int), stream);
    hipMemsetAsync(loss_accum, 0, sizeof(float), stream);
    cvt_h_kernel<<<(N * 32) / 256, 256, 0, stream>>>(x, x16);
    cvt_h_kernel<<<(K * 32) / 256, 256, 0, stream>>>(cb, cb16);
    enorm_kernel<<<(K * 64) / 256, 256, 0, stream>>>(cb, en, K);
    vq_mfma_kernel<<<N / BM, 256, 0, stream>>>(x16, cb16, en, bidx, list, counter);
    rescan_kernel<<<512, 256, 0, stream>>>(x, cb, en, list, counter, bidx);
    gather_kernel<<<N / 64, 256, 0, stream>>>(x, cb, bidx, out, loss_accum, N);
    loss_fin_kernel<<<1, 64, 0, stream>>>(loss_accum, out, (size_t)N * DDIM);
}